// Round 8
// baseline (1059.603 us; speedup 1.0000x reference)
//
#include <hip/hip_runtime.h>
#include <hip/hip_bf16.h>

// ---------------- problem constants ----------------
#define T_LEN 1048576
#define FL    1024
#define PADL  512
#define HOP   256
#define NFR   4097            // frames per batch
#define NB    8
#define NTOT  32776           // NB*NFR
#define XP2   1049600         // T_LEN + FL (reflect-padded length per batch)
#define M_OUT 1026
#define BM 256
#define BN 256
#define MT 4                  // 1024 rows
#define NT 128                // 32768 frames in main GEMM
#define NWGM 512              // MT*NT -> all co-resident at 2 blocks/CU
#define TAIL_ROW 1025         // ceil(NTOT/32)
#define TAIL_BLKS 1089        // + 64 frame-tail blocks

typedef __bf16 bf16x8 __attribute__((ext_vector_type(8)));
typedef float  f32x4  __attribute__((ext_vector_type(4)));

__device__ __forceinline__ void gload16(const __hip_bfloat16* g, void* l) {
  __builtin_amdgcn_global_load_lds(
      (const __attribute__((address_space(1))) unsigned int*)g,
      (__attribute__((address_space(3))) unsigned int*)l, 16, 0, 0);
}

__device__ __forceinline__ float bf2f(unsigned short h) {
  union { unsigned u; float f; } c; c.u = ((unsigned)h) << 16; return c.f;
}

// ---------------- prep: reflect-pad x, convert to bf16 (8 elems/thread) ----------------
__global__ __launch_bounds__(256) void pad_convert_x8(
    const float* __restrict__ x, __hip_bfloat16* __restrict__ xp) {
  const int base = (blockIdx.x * 256 + threadIdx.x) * 8;
  const int b = blockIdx.y;
  if (base >= XP2) return;
  const float* __restrict__ xb = x + (size_t)b * T_LEN;
  union { bf16x8 v; __hip_bfloat16 h[8]; } o;
  if (base >= PADL && base + 8 <= PADL + T_LEN) {
    const float4 v0 = *(const float4*)&xb[base - PADL];
    const float4 v1 = *(const float4*)&xb[base - PADL + 4];
    o.h[0] = __float2bfloat16(v0.x); o.h[1] = __float2bfloat16(v0.y);
    o.h[2] = __float2bfloat16(v0.z); o.h[3] = __float2bfloat16(v0.w);
    o.h[4] = __float2bfloat16(v1.x); o.h[5] = __float2bfloat16(v1.y);
    o.h[6] = __float2bfloat16(v1.z); o.h[7] = __float2bfloat16(v1.w);
    *(bf16x8*)&xp[(size_t)b * XP2 + base] = o.v;
  } else {
    for (int e = 0; e < 8; ++e) {
      const int i = base + e;
      if (i < XP2) {
        const int t = i - PADL;
        const int idx = (t < 0) ? -t : ((t >= T_LEN) ? (2 * T_LEN - 2 - t) : t);
        xp[(size_t)b * XP2 + i] = __float2bfloat16(xb[idx]);
      }
    }
  }
}

// ---------------- prep: basis rows 0..1023 to bf16 (8 elems/thread) ----------------
__global__ __launch_bounds__(256) void convert_basis8(
    const float* __restrict__ basis, __hip_bfloat16* __restrict__ bb) {
  const int base = (blockIdx.x * 256 + threadIdx.x) * 8;
  if (base >= 1024 * FL) return;
  const float4 v0 = *(const float4*)&basis[base];
  const float4 v1 = *(const float4*)&basis[base + 4];
  union { bf16x8 v; __hip_bfloat16 h[8]; } o;
  o.h[0] = __float2bfloat16(v0.x); o.h[1] = __float2bfloat16(v0.y);
  o.h[2] = __float2bfloat16(v0.z); o.h[3] = __float2bfloat16(v0.w);
  o.h[4] = __float2bfloat16(v1.x); o.h[5] = __float2bfloat16(v1.y);
  o.h[6] = __float2bfloat16(v1.z); o.h[7] = __float2bfloat16(v1.w);
  *(bf16x8*)&bb[base] = o.v;
}

// ---------------- main GEMM: 256x256, BK=32, A direct-to-reg, B LDS-staged ----------------
// A fragments loaded global->VGPR (L1-dedup'd across 4 sharing waves),
// lead-1 reg double-buffer (aA/aB). B staged via gload_lds, 4 slots (64 KB
// -> 2 blocks/CU, all 512 blocks resident). Per tile: {RD_B(4 ds_read),
// LOAD_A(T+1) 8 dwordx4, STAGE_B(T+3) 2 gloads, 32 MFMA, vmcnt(2), barrier}.
__global__ __launch_bounds__(512, 4) void stft_gemm9(
    const __hip_bfloat16* __restrict__ A,   // [1024][FL]
    const __hip_bfloat16* __restrict__ X,   // [NB][XP2]
    float* __restrict__ out) {              // [NB][M_OUT][NFR]
  __shared__ __hip_bfloat16 Bs[4][256 * 32];   // 4 x 16 KB

  // XCD swizzle (512 % 8 == 0)
  const int orig = blockIdx.x;
  const int wg = (orig & 7) * (NWGM / 8) + (orig >> 3);
  const int mtile = wg & 3, ntile = wg >> 2;
  const int tileM = mtile * BM, tileN = ntile * BN;

  const int tid = threadIdx.x;
  const int w = tid >> 6, l = tid & 63;     // 8 waves
  const int wm = w >> 2, wn = w & 3;        // 2M x 4N; per-wave 128x64

  // ---- B staging addressing (pre-swizzled global source, linear LDS dest) ----
  const int g_log = (l & 3) ^ ((l >> 3) & 3);
  const int srow = l >> 2;
  const __hip_bfloat16* bBase[2];
#pragma unroll
  for (int j = 0; j < 2; ++j) {
    const int c = j * 8 + w;
    const int fg = tileN + c * 16 + srow;            // < 32768
    const int bb = fg / NFR;
    const int fb = fg - bb * NFR;
    bBase[j] = X + (size_t)bb * XP2 + (size_t)fb * HOP + g_log * 8;
  }

  // ---- B fragment read addressing (swizzled; 2-way bank alias = free) ----
  const int swz = ((l >> 4) ^ ((l >> 1) & 3)) * 8;
  const int bIdx = (wn * 64 + (l & 15)) * 32 + swz;

  // ---- A direct global pointers: lane l -> row tileM+wm*128+m*16+(l&15),
  //      k-group (l>>4)*8 (same logical fragment the LDS path produced) ----
  const __hip_bfloat16* aPtr[8];
#pragma unroll
  for (int m = 0; m < 8; ++m)
    aPtr[m] = A + (size_t)(tileM + wm * 128 + m * 16 + (l & 15)) * FL + (l >> 4) * 8;

  f32x4 acc[8][4] = {};
  bf16x8 aA[8], aB[8], bfr[4];

#define LOAD_A(dst_, KO_) do {                                               \
    _Pragma("unroll") for (int m = 0; m < 8; ++m)                            \
      dst_[m] = *(const bf16x8*)(aPtr[m] + (KO_));                           \
  } while (0)

#define STAGE_B(KO_, SL_) do {                                               \
    _Pragma("unroll") for (int j = 0; j < 2; ++j)                            \
      gload16(bBase[j] + (KO_), (void*)&Bs[SL_][(j*8 + w)*512]);             \
  } while (0)

#define RD_B(SL_) do {                                                       \
    _Pragma("unroll") for (int nn = 0; nn < 4; ++nn)                         \
      bfr[nn] = *(const bf16x8*)&Bs[SL_][bIdx + nn*512];                     \
  } while (0)

#define MM_ALL(afx_) do {                                                    \
    __builtin_amdgcn_s_setprio(1);                                           \
    _Pragma("unroll") for (int mm = 0; mm < 8; ++mm)                         \
      _Pragma("unroll") for (int nn = 0; nn < 4; ++nn)                       \
        acc[mm][nn] = __builtin_amdgcn_mfma_f32_16x16x32_bf16(               \
            afx_[mm], bfr[nn], acc[mm][nn], 0, 0, 0);                        \
    __builtin_amdgcn_s_setprio(0);                                           \
  } while (0)

#define BAR __builtin_amdgcn_s_barrier()
#define SB  __builtin_amdgcn_sched_barrier(0)

  // TILE: T_=tile idx, ACUR_/ANXT_=named A reg sets, DOA_=load A(T+1),
  // DOSTG_=stage B(T+3), VM_=vmcnt literal
#define TILE(T_, ACUR_, ANXT_, DOA_, DOSTG_, VM_) do {                       \
    SB;                                                                      \
    RD_B((T_) & 3);                                                          \
    if (DOA_) LOAD_A(ANXT_, ((T_) + 1) * 32);                                \
    if (DOSTG_) STAGE_B(((T_) + 3) * 32, ((T_) + 3) & 3);                    \
    MM_ALL(ACUR_);                                                           \
    asm volatile("s_waitcnt vmcnt(" #VM_ ")" ::: "memory");                  \
    BAR;                                                                     \
  } while (0)

  // prologue: stage B tiles 0,1,2; load A tile 0; full drain once
  STAGE_B(0, 0); STAGE_B(32, 1); STAGE_B(64, 2);
  LOAD_A(aA, 0);
  asm volatile("s_waitcnt vmcnt(0)" ::: "memory");
  BAR;

  for (int p = 0; p < 28; p += 2) {          // tiles 0..27 (all stage B(T+3))
    TILE(p, aA, aB, 1, 1, 2);
    TILE(p + 1, aB, aA, 1, 1, 2);
  }
  TILE(28, aA, aB, 1, 1, 2);                 // stages B31 -> slot 3
  TILE(29, aB, aA, 1, 0, 0);                 // loads A30; drain
  TILE(30, aA, aB, 1, 0, 0);                 // loads A31; drain
  // tile 31 peeled: no loads, no barrier
  SB;
  RD_B(3);
  MM_ALL(aB);

#undef TILE
#undef BAR
#undef SB
#undef MM_ALL
#undef RD_B
#undef STAGE_B
#undef LOAD_A

  // ---- epilogue: C/D layout col = lane&15 (frame), row = (lane>>4)*4 + j ----
  const int cn = l & 15, rb = (l >> 4) * 4;
  size_t obase[4];
#pragma unroll
  for (int n = 0; n < 4; ++n) {
    const int fg = tileN + wn * 64 + n * 16 + cn;   // < 32768
    const int bb = fg / NFR;
    const int fb = fg - bb * NFR;
    obase[n] = (size_t)bb * M_OUT * NFR + fb;
  }
#pragma unroll
  for (int m = 0; m < 8; ++m) {
    const int o0 = tileM + wm * 128 + m * 16 + rb;  // < 1024
#pragma unroll
    for (int j = 0; j < 4; ++j) {
      const int o = o0 + j;
#pragma unroll
      for (int n = 0; n < 4; ++n)
        out[obase[n] + (size_t)o * NFR] = acc[m][n][j];
    }
  }
}

// ---------------- tail: rows 1024/1025 (all frames) + frames 32768..32775 ----------------
__global__ __launch_bounds__(256) void stft_tail3(
    const float* __restrict__ basis,            // [1026][1024] f32
    const __hip_bfloat16* __restrict__ xp,      // [NB][XP2]
    const __hip_bfloat16* __restrict__ basisBf, // [1024][1024]
    float* __restrict__ out) {
  const int blk = blockIdx.x;
  if (blk < TAIL_ROW) {
    // rows 1024/1025, 32 frames/block, K-split 8x128 + LDS reduce
    __shared__ float b0[1024], b1[1024];
    __shared__ float part[2][8][32];
    for (int i = threadIdx.x; i < 1024; i += 256) {
      b0[i] = basis[1024 * 1024 + i];
      b1[i] = basis[1025 * 1024 + i];
    }
    __syncthreads();
    const int fl = threadIdx.x & 31, ks = threadIdx.x >> 5;
    const int fg = blk * 32 + fl;
    float s0 = 0.f, s1 = 0.f;
    if (fg < NTOT) {
      const int b = fg / NFR, fb = fg - b * NFR;
      const __hip_bfloat16* w = xp + (size_t)b * XP2 + (size_t)fb * HOP + ks * 128;
      const float* bb0 = b0 + ks * 128;
      const float* bb1 = b1 + ks * 128;
#pragma unroll 4
      for (int k = 0; k < 128; k += 8) {
        union { bf16x8 v; unsigned short u[8]; } uu;
        uu.v = *(const bf16x8*)&w[k];
#pragma unroll
        for (int j = 0; j < 8; ++j) {
          const float xv = bf2f(uu.u[j]);
          s0 += bb0[k + j] * xv;
          s1 += bb1[k + j] * xv;
        }
      }
    }
    part[0][ks][fl] = s0;
    part[1][ks][fl] = s1;
    __syncthreads();
    if (threadIdx.x < 64) {
      const int row = threadIdx.x >> 5, f = threadIdx.x & 31;
      const int fg2 = blk * 32 + f;
      if (fg2 < NTOT) {
        float s = 0.f;
#pragma unroll
        for (int k2 = 0; k2 < 8; ++k2) s += part[row][k2][f];
        const int b = fg2 / NFR, fb = fg2 - b * NFR;
        out[((size_t)b * M_OUT + 1024 + row) * NFR + fb] = s;
      }
    }
  } else {
    // frames 32768..32775 (batch 7) x rows 0..1023; block = (frame, 128-row group)
    const int idx = blk - TAIL_ROW;          // 0..63
    const int f8 = idx >> 3, rg = idx & 7;
    const int fb = 4089 + f8;                // fg - 7*NFR
    __shared__ __hip_bfloat16 win[1024];
    const __hip_bfloat16* w = xp + (size_t)7 * XP2 + (size_t)fb * HOP;
    for (int i = threadIdx.x; i < 1024; i += 256) win[i] = w[i];
    __syncthreads();
    const int r = rg * 128 + (threadIdx.x >> 1);
    const int kh = threadIdx.x & 1;
    const __hip_bfloat16* br = basisBf + (size_t)r * FL + kh * 512;
    const __hip_bfloat16* wk = win + kh * 512;
    float s = 0.f;
    for (int k = 0; k < 512; k += 8) {
      union { bf16x8 v; unsigned short u[8]; } ub, ux;
      ub.v = *(const bf16x8*)&br[k];
      ux.v = *(const bf16x8*)&wk[k];
#pragma unroll
      for (int j = 0; j < 8; ++j) s += bf2f(ub.u[j]) * bf2f(ux.u[j]);
    }
    s += __shfl_xor(s, 1);
    if (kh == 0) out[((size_t)7 * M_OUT + r) * NFR + fb] = s;
  }
}

extern "C" void kernel_launch(void* const* d_in, const int* in_sizes, int n_in,
                              void* d_out, int out_size, void* d_ws, size_t ws_size,
                              hipStream_t stream) {
  const float* x = (const float*)d_in[0];       // [8, 1048576] f32
  const float* basis = (const float*)d_in[1];   // [1026, 1, 1024] f32
  float* out = (float*)d_out;                   // [8, 1026, 4097] f32

  __hip_bfloat16* xpBf = (__hip_bfloat16*)d_ws;                 // NB*XP2 bf16
  __hip_bfloat16* basisBf = xpBf + (size_t)NB * XP2;            // 1024*FL bf16

  dim3 gPad((XP2 / 8 + 255) / 256, NB);
  pad_convert_x8<<<gPad, 256, 0, stream>>>(x, xpBf);

  convert_basis8<<<(1024 * FL / 8) / 256, 256, 0, stream>>>(basis, basisBf);

  stft_gemm9<<<NWGM, 512, 0, stream>>>(basisBf, xpBf, out);
  stft_tail3<<<TAIL_BLKS, 256, 0, stream>>>(basis, xpBf, basisBf, out);
}

// Round 9
// 178.934 us; speedup vs baseline: 5.9218x; 5.9218x over previous
//
#include <hip/hip_runtime.h>
#include <hip/hip_bf16.h>

// ---------------- problem constants ----------------
#define T_LEN 1048576
#define FL    1024
#define PADL  512
#define HOP   256
#define NFR   4097            // frames per batch
#define NB    8
#define NTOT  32776           // NB*NFR
#define XP2   1049600         // T_LEN + FL (reflect-padded length per batch)
#define M_OUT 1026
#define BM 256
#define BN 256
#define MT 4                  // 1024 rows
#define NT 128                // 32768 frames in main GEMM
#define NWGM 512              // MT*NT
#define TAIL_ROW 1025         // ceil(NTOT/32)
#define TAIL_BLKS 1089        // + 64 frame-tail blocks

typedef __bf16 bf16x8 __attribute__((ext_vector_type(8)));
typedef float  f32x4  __attribute__((ext_vector_type(4)));

__device__ __forceinline__ void gload16(const __hip_bfloat16* g, void* l) {
  __builtin_amdgcn_global_load_lds(
      (const __attribute__((address_space(1))) unsigned int*)g,
      (__attribute__((address_space(3))) unsigned int*)l, 16, 0, 0);
}

__device__ __forceinline__ float bf2f(unsigned short h) {
  union { unsigned u; float f; } c; c.u = ((unsigned)h) << 16; return c.f;
}

// ---------------- prep: reflect-pad x, convert to bf16 (8 elems/thread) ----------------
__global__ __launch_bounds__(256) void pad_convert_x8(
    const float* __restrict__ x, __hip_bfloat16* __restrict__ xp) {
  const int base = (blockIdx.x * 256 + threadIdx.x) * 8;
  const int b = blockIdx.y;
  if (base >= XP2) return;
  const float* __restrict__ xb = x + (size_t)b * T_LEN;
  union { bf16x8 v; __hip_bfloat16 h[8]; } o;
  if (base >= PADL && base + 8 <= PADL + T_LEN) {
    const float4 v0 = *(const float4*)&xb[base - PADL];
    const float4 v1 = *(const float4*)&xb[base - PADL + 4];
    o.h[0] = __float2bfloat16(v0.x); o.h[1] = __float2bfloat16(v0.y);
    o.h[2] = __float2bfloat16(v0.z); o.h[3] = __float2bfloat16(v0.w);
    o.h[4] = __float2bfloat16(v1.x); o.h[5] = __float2bfloat16(v1.y);
    o.h[6] = __float2bfloat16(v1.z); o.h[7] = __float2bfloat16(v1.w);
    *(bf16x8*)&xp[(size_t)b * XP2 + base] = o.v;
  } else {
    for (int e = 0; e < 8; ++e) {
      const int i = base + e;
      if (i < XP2) {
        const int t = i - PADL;
        const int idx = (t < 0) ? -t : ((t >= T_LEN) ? (2 * T_LEN - 2 - t) : t);
        xp[(size_t)b * XP2 + i] = __float2bfloat16(xb[idx]);
      }
    }
  }
}

// ---------------- prep: basis rows 0..1023 to bf16 (8 elems/thread) ----------------
__global__ __launch_bounds__(256) void convert_basis8(
    const float* __restrict__ basis, __hip_bfloat16* __restrict__ bb) {
  const int base = (blockIdx.x * 256 + threadIdx.x) * 8;
  if (base >= 1024 * FL) return;
  const float4 v0 = *(const float4*)&basis[base];
  const float4 v1 = *(const float4*)&basis[base + 4];
  union { bf16x8 v; __hip_bfloat16 h[8]; } o;
  o.h[0] = __float2bfloat16(v0.x); o.h[1] = __float2bfloat16(v0.y);
  o.h[2] = __float2bfloat16(v0.z); o.h[3] = __float2bfloat16(v0.w);
  o.h[4] = __float2bfloat16(v1.x); o.h[5] = __float2bfloat16(v1.y);
  o.h[6] = __float2bfloat16(v1.z); o.h[7] = __float2bfloat16(v1.w);
  *(bf16x8*)&bb[base] = o.v;
}

// ---------------- main GEMM: 256x256, BK=32, A global->reg, B LDS-staged ----------------
// A fragments: direct global->VGPR (L1-dedup'd across the 4 waves sharing
// each A-panel), 2 named 4-frag sets, loaded one m-half phase ahead.
// B: gload_lds into 4 slots (64 KB), lead-3, zero-conflict swizzle.
// Per tile: ph0 {4 ds_read B, 4 A-loads (h1), stage B(t+3), vmcnt(6),
// 16 MFMA(h0)}; ph1 {4 A-loads (t+1,h0), vmcnt(6), 16 MFMA(h1), barrier}.
__global__ __launch_bounds__(512, 2) void stft_gemm9(
    const __hip_bfloat16* __restrict__ A,   // [1024][FL]
    const __hip_bfloat16* __restrict__ X,   // [NB][XP2]
    float* __restrict__ out) {              // [NB][M_OUT][NFR]
  __shared__ __hip_bfloat16 Bs[4][256 * 32];   // 4 x 16 KB

  // XCD swizzle (512 % 8 == 0)
  const int orig = blockIdx.x;
  const int wg = (orig & 7) * (NWGM / 8) + (orig >> 3);
  const int mtile = wg & 3, ntile = wg >> 2;
  const int tileM = mtile * BM, tileN = ntile * BN;

  const int tid = threadIdx.x;
  const int w = tid >> 6, l = tid & 63;     // 8 waves
  const int wm = w >> 2, wn = w & 3;        // 2M x 4N; per-wave 128x64

  // ---- B staging addressing (pre-swizzled global source, linear LDS dest) ----
  const int g_log = (l & 3) ^ ((l >> 3) & 3);
  const int srow = l >> 2;
  const __hip_bfloat16* bBase[2];
#pragma unroll
  for (int j = 0; j < 2; ++j) {
    const int c = j * 8 + w;
    const int fg = tileN + c * 16 + srow;            // < 32768
    const int bb = fg / NFR;
    const int fb = fg - bb * NFR;
    bBase[j] = X + (size_t)bb * XP2 + (size_t)fb * HOP + g_log * 8;
  }

  // ---- B fragment read addressing (swizzled; 2-way bank alias = free) ----
  const int swz = ((l >> 4) ^ ((l >> 1) & 3)) * 8;
  const int bIdx = (wn * 64 + (l & 15)) * 32 + swz;

  // ---- A direct global pointers: frag m -> row tileM+wm*128+m*16+(l&15),
  //      k-group (l>>4)*8 (identical logical fragment to the LDS path) ----
  const __hip_bfloat16* aPtr[8];
#pragma unroll
  for (int m = 0; m < 8; ++m)
    aPtr[m] = A + (size_t)(tileM + wm * 128 + m * 16 + (l & 15)) * FL + (l >> 4) * 8;

  f32x4 acc[8][4] = {};
  bf16x8 aCur[4], aNxt[4], bfr[4];

#define LOAD_A(dst_, KO_, H_) do {                                           \
    _Pragma("unroll") for (int mm = 0; mm < 4; ++mm)                         \
      dst_[mm] = *(const bf16x8*)(aPtr[(H_) * 4 + mm] + (KO_));              \
  } while (0)

#define STAGE_B(KO_, SL_) do {                                               \
    _Pragma("unroll") for (int j = 0; j < 2; ++j)                            \
      gload16(bBase[j] + (KO_), (void*)&Bs[SL_][(j*8 + w)*512]);             \
  } while (0)

#define RD_B(SL_) do {                                                       \
    _Pragma("unroll") for (int nn = 0; nn < 4; ++nn)                         \
      bfr[nn] = *(const bf16x8*)&Bs[SL_][bIdx + nn*512];                     \
  } while (0)

#define MM(afx_, MH_) do {                                                   \
    __builtin_amdgcn_s_setprio(1);                                           \
    _Pragma("unroll") for (int mm = 0; mm < 4; ++mm)                         \
      _Pragma("unroll") for (int nn = 0; nn < 4; ++nn)                       \
        acc[(MH_)*4 + mm][nn] = __builtin_amdgcn_mfma_f32_16x16x32_bf16(     \
            afx_[mm], bfr[nn], acc[(MH_)*4 + mm][nn], 0, 0, 0);              \
    __builtin_amdgcn_s_setprio(0);                                           \
  } while (0)

#define BAR __builtin_amdgcn_s_barrier()
#define SB  __builtin_amdgcn_sched_barrier(0)
#define VMC(N_) asm volatile("s_waitcnt vmcnt(" #N_ ")" ::: "memory")

  // prologue: stage B0,B1,B2; load A(0,h0); land B0 (and A via compiler wait)
  STAGE_B(0, 0); STAGE_B(32, 1); STAGE_B(64, 2);
  LOAD_A(aCur, 0, 0);
  VMC(4);
  BAR;

  for (int t = 0; t < 28; ++t) {            // steady tiles 0..27
    SB;
    RD_B(t & 3);
    LOAD_A(aNxt, t * 32, 1);
    STAGE_B((t + 3) * 32, (t + 3) & 3);
    VMC(6);
    MM(aCur, 0);
    SB;
    LOAD_A(aCur, (t + 1) * 32, 0);
    VMC(6);
    MM(aNxt, 1);
    BAR;
  }
  // t = 28 (stages B31 -> slot 3)
  SB; RD_B(0); LOAD_A(aNxt, 28 * 32, 1); STAGE_B(31 * 32, 3);
  VMC(6); MM(aCur, 0);
  SB; LOAD_A(aCur, 29 * 32, 0);
  VMC(6); MM(aNxt, 1); BAR;
  // t = 29 (no more stages; no more barriers needed)
  SB; RD_B(1); LOAD_A(aNxt, 29 * 32, 1);
  VMC(4); MM(aCur, 0);
  SB; LOAD_A(aCur, 30 * 32, 0);
  VMC(4); MM(aNxt, 1);
  // t = 30
  SB; RD_B(2); LOAD_A(aNxt, 30 * 32, 1);
  VMC(4); MM(aCur, 0);
  SB; LOAD_A(aCur, 31 * 32, 0);
  VMC(4); MM(aNxt, 1);
  // t = 31
  SB; RD_B(3); LOAD_A(aNxt, 31 * 32, 1);
  VMC(4); MM(aCur, 0);
  SB;
  VMC(0); MM(aNxt, 1);

#undef VMC
#undef BAR
#undef SB
#undef MM
#undef RD_B
#undef STAGE_B
#undef LOAD_A

  // ---- epilogue: C/D layout col = lane&15 (frame), row = (lane>>4)*4 + j ----
  const int cn = l & 15, rb = (l >> 4) * 4;
  size_t obase[4];
#pragma unroll
  for (int n = 0; n < 4; ++n) {
    const int fg = tileN + wn * 64 + n * 16 + cn;   // < 32768
    const int bb = fg / NFR;
    const int fb = fg - bb * NFR;
    obase[n] = (size_t)bb * M_OUT * NFR + fb;
  }
#pragma unroll
  for (int m = 0; m < 8; ++m) {
    const int o0 = tileM + wm * 128 + m * 16 + rb;  // < 1024
#pragma unroll
    for (int j = 0; j < 4; ++j) {
      const int o = o0 + j;
#pragma unroll
      for (int n = 0; n < 4; ++n)
        out[obase[n] + (size_t)o * NFR] = acc[m][n][j];
    }
  }
}

// ---------------- tail: rows 1024/1025 (all frames) + frames 32768..32775 ----------------
__global__ __launch_bounds__(256) void stft_tail3(
    const float* __restrict__ basis,            // [1026][1024] f32
    const __hip_bfloat16* __restrict__ xp,      // [NB][XP2]
    const __hip_bfloat16* __restrict__ basisBf, // [1024][1024]
    float* __restrict__ out) {
  const int blk = blockIdx.x;
  if (blk < TAIL_ROW) {
    // rows 1024/1025, 32 frames/block, K-split 8x128 + LDS reduce
    __shared__ float b0[1024], b1[1024];
    __shared__ float part[2][8][32];
    for (int i = threadIdx.x; i < 1024; i += 256) {
      b0[i] = basis[1024 * 1024 + i];
      b1[i] = basis[1025 * 1024 + i];
    }
    __syncthreads();
    const int fl = threadIdx.x & 31, ks = threadIdx.x >> 5;
    const int fg = blk * 32 + fl;
    float s0 = 0.f, s1 = 0.f;
    if (fg < NTOT) {
      const int b = fg / NFR, fb = fg - b * NFR;
      const __hip_bfloat16* w = xp + (size_t)b * XP2 + (size_t)fb * HOP + ks * 128;
      const float* bb0 = b0 + ks * 128;
      const float* bb1 = b1 + ks * 128;
#pragma unroll 4
      for (int k = 0; k < 128; k += 8) {
        union { bf16x8 v; unsigned short u[8]; } uu;
        uu.v = *(const bf16x8*)&w[k];
#pragma unroll
        for (int j = 0; j < 8; ++j) {
          const float xv = bf2f(uu.u[j]);
          s0 += bb0[k + j] * xv;
          s1 += bb1[k + j] * xv;
        }
      }
    }
    part[0][ks][fl] = s0;
    part[1][ks][fl] = s1;
    __syncthreads();
    if (threadIdx.x < 64) {
      const int row = threadIdx.x >> 5, f = threadIdx.x & 31;
      const int fg2 = blk * 32 + f;
      if (fg2 < NTOT) {
        float s = 0.f;
#pragma unroll
        for (int k2 = 0; k2 < 8; ++k2) s += part[row][k2][f];
        const int b = fg2 / NFR, fb = fg2 - b * NFR;
        out[((size_t)b * M_OUT + 1024 + row) * NFR + fb] = s;
      }
    }
  } else {
    // frames 32768..32775 (batch 7) x rows 0..1023; block = (frame, 128-row group)
    const int idx = blk - TAIL_ROW;          // 0..63
    const int f8 = idx >> 3, rg = idx & 7;
    const int fb = 4089 + f8;                // fg - 7*NFR
    __shared__ __hip_bfloat16 win[1024];
    const __hip_bfloat16* w = xp + (size_t)7 * XP2 + (size_t)fb * HOP;
    for (int i = threadIdx.x; i < 1024; i += 256) win[i] = w[i];
    __syncthreads();
    const int r = rg * 128 + (threadIdx.x >> 1);
    const int kh = threadIdx.x & 1;
    const __hip_bfloat16* br = basisBf + (size_t)r * FL + kh * 512;
    const __hip_bfloat16* wk = win + kh * 512;
    float s = 0.f;
    for (int k = 0; k < 512; k += 8) {
      union { bf16x8 v; unsigned short u[8]; } ub, ux;
      ub.v = *(const bf16x8*)&br[k];
      ux.v = *(const bf16x8*)&wk[k];
#pragma unroll
      for (int j = 0; j < 8; ++j) s += bf2f(ub.u[j]) * bf2f(ux.u[j]);
    }
    s += __shfl_xor(s, 1);
    if (kh == 0) out[((size_t)7 * M_OUT + r) * NFR + fb] = s;
  }
}

extern "C" void kernel_launch(void* const* d_in, const int* in_sizes, int n_in,
                              void* d_out, int out_size, void* d_ws, size_t ws_size,
                              hipStream_t stream) {
  const float* x = (const float*)d_in[0];       // [8, 1048576] f32
  const float* basis = (const float*)d_in[1];   // [1026, 1, 1024] f32
  float* out = (float*)d_out;                   // [8, 1026, 4097] f32

  __hip_bfloat16* xpBf = (__hip_bfloat16*)d_ws;                 // NB*XP2 bf16
  __hip_bfloat16* basisBf = xpBf + (size_t)NB * XP2;            // 1024*FL bf16

  dim3 gPad((XP2 / 8 + 255) / 256, NB);
  pad_convert_x8<<<gPad, 256, 0, stream>>>(x, xpBf);

  convert_basis8<<<(1024 * FL / 8) / 256, 256, 0, stream>>>(basis, basisBf);

  stft_gemm9<<<NWGM, 512, 0, stream>>>(basisBf, xpBf, out);
  stft_tail3<<<TAIL_BLKS, 256, 0, stream>>>(basis, xpBf, basisBf, out);
}

// Round 10
// 101.301 us; speedup vs baseline: 10.4599x; 1.7664x over previous
//
#include <hip/hip_runtime.h>
#include <hip/hip_bf16.h>

// ---------------- problem constants ----------------
#define T_LEN 1048576
#define FL    1024
#define PADL  512
#define HOP   256
#define NFR   4097            // frames per batch
#define NB    8
#define XP2   1049600         // reflect-padded length per batch = 4100*256
#define NSEG  4100            // segments per batch
#define MROWS 1028            // 2*(513+1) interleaved re/im rows, k=0..513
#define MPAD  1152            // padded C-matrix rows
#define MTL   9               // M-tiles (stride 124 rows = 62 k)
#define FTL   33              // frame-tiles per batch (stride 125 frames)
#define NTL   264             // FTL*NB
#define NWG2  2376            // MTL*NTL (divisible by 8)

typedef __bf16 bf16x8 __attribute__((ext_vector_type(8)));
typedef float  f32x4  __attribute__((ext_vector_type(4)));

__device__ __forceinline__ void gload16(const __hip_bfloat16* g, void* l) {
  __builtin_amdgcn_global_load_lds(
      (const __attribute__((address_space(1))) unsigned int*)g,
      (__attribute__((address_space(3))) unsigned int*)l, 16, 0, 0);
}

// ---------------- prep: reflect-pad x, convert to bf16 (8 elems/thread) ----------------
__global__ __launch_bounds__(256) void pad_convert_x8(
    const float* __restrict__ x, __hip_bfloat16* __restrict__ xp) {
  const int base = (blockIdx.x * 256 + threadIdx.x) * 8;
  const int b = blockIdx.y;
  if (base >= XP2) return;
  const float* __restrict__ xb = x + (size_t)b * T_LEN;
  union { bf16x8 v; __hip_bfloat16 h[8]; } o;
  if (base >= PADL && base + 8 <= PADL + T_LEN) {
    const float4 v0 = *(const float4*)&xb[base - PADL];
    const float4 v1 = *(const float4*)&xb[base - PADL + 4];
    o.h[0] = __float2bfloat16(v0.x); o.h[1] = __float2bfloat16(v0.y);
    o.h[2] = __float2bfloat16(v0.z); o.h[3] = __float2bfloat16(v0.w);
    o.h[4] = __float2bfloat16(v1.x); o.h[5] = __float2bfloat16(v1.y);
    o.h[6] = __float2bfloat16(v1.z); o.h[7] = __float2bfloat16(v1.w);
    *(bf16x8*)&xp[(size_t)b * XP2 + base] = o.v;
  } else {
    for (int e = 0; e < 8; ++e) {
      const int i = base + e;
      if (i < XP2) {
        const int t = i - PADL;
        const int idx = (t < 0) ? -t : ((t >= T_LEN) ? (2 * T_LEN - 2 - t) : t);
        xp[(size_t)b * XP2 + i] = __float2bfloat16(xb[idx]);
      }
    }
  }
}

// ---------------- prep: build segment-DFT matrix, bf16 [MPAD][256] ----------------
// row 2k   = cos(2*pi*k*r/1024), row 2k+1 = -sin(2*pi*k*r/1024), k = 0..513
__global__ __launch_bounds__(256) void build_cmat(__hip_bfloat16* __restrict__ cm) {
  const int idx = blockIdx.x * 256 + threadIdx.x;   // over MPAD*256
  if (idx >= MPAD * 256) return;
  const int row = idx >> 8, r = idx & 255;
  float v = 0.f;
  if (row < MROWS) {
    const int k = row >> 1;
    const int ph = (k * r) & 1023;
    const float ang = (float)ph * 6.2831853071795864769e-0f / 1024.f;
    v = (row & 1) ? -sinf(ang) : cosf(ang);
  }
  cm[idx] = __float2bfloat16(v);
}

// ---------------- fused segment-GEMM + hann-conv combine ----------------
// U-tile GEMM: 128 M-rows (64 k, re/im interleaved) x 128 segments, K=256
// (8 BK=32 tiles, 3 LDS slots, lead-2, vmcnt(4)). Then U -> LDS (f32) and
// per-(k,f) combine: Z[kk,f] = sum_q (-i)^(kk*q) U[kk,f+q] (sign/swap only),
// Y = 0.5 Z[k] - 0.25 Z[k-1] - 0.25 Z[k+1]; out rows k (Re) and 513+k (Im).
__global__ __launch_bounds__(256, 2) void stft_fgemm(
    const __hip_bfloat16* __restrict__ Cm,  // [MPAD][256]
    const __hip_bfloat16* __restrict__ X,   // [NB][XP2]
    float* __restrict__ out) {              // [NB][1026][4097]
  __shared__ char ldsraw[128 * 132 * 4];    // 67584 B; staging aliases first 48 KB
  __hip_bfloat16* stg = (__hip_bfloat16*)ldsraw;
  float* Ub = (float*)ldsraw;

  // XCD swizzle (2376 % 8 == 0); consecutive wg share the N-tile (B reuse)
  const int orig = blockIdx.x;
  const int wg = (orig & 7) * (NWG2 / 8) + (orig >> 3);
  const int mt = wg % MTL;
  const int nt = wg / MTL;
  const int b = nt / FTL, ft = nt % FTL;
  const int gb = ft * 125;                  // segment/frame base
  const int RB = mt * 124;                  // C-matrix row base

  const int tid = threadIdx.x;
  const int w = tid >> 6, l = tid & 63;     // 4 waves
  const int wm = w >> 1, wn = w & 1;        // 2M x 2N; per-wave 64x64

  // ---- staging addressing (pre-swizzled global source, linear LDS dest) ----
  const int g_log = (l & 3) ^ ((l >> 3) & 3);
  const int srow = l >> 2;
  const __hip_bfloat16* aB_[2];
  const __hip_bfloat16* bB_[2];
#pragma unroll
  for (int j = 0; j < 2; ++j) {
    const int c = w * 2 + j;                // chunks 0..7 (16 rows each)
    aB_[j] = Cm + (size_t)(RB + c * 16 + srow) * 256 + g_log * 8;
    int g = gb + c * 16 + srow;
    if (g > NSEG - 1) g = NSEG - 1;         // clamp (outputs guarded)
    bB_[j] = X + (size_t)b * XP2 + (size_t)g * 256 + g_log * 8;
  }

  // ---- fragment read addressing (swizzled; verified conflict-free) ----
  const int swz = ((l >> 4) ^ ((l >> 1) & 3)) * 8;
  const int aIdx = (wm * 64 + (l & 15)) * 32 + swz;          // + m*512
  const int bIdx = 4096 + (wn * 64 + (l & 15)) * 32 + swz;   // + n*512

  f32x4 acc[4][4] = {};

#define STAGE(K0_, S_) do {                                                  \
    _Pragma("unroll") for (int j = 0; j < 2; ++j) {                          \
      const int c_ = w * 2 + j;                                              \
      gload16(aB_[j] + (K0_), (void*)(stg + (S_) * 8192 + c_ * 512));        \
      gload16(bB_[j] + (K0_), (void*)(stg + (S_) * 8192 + 4096 + c_ * 512)); \
    }                                                                        \
  } while (0)

#define RDMM(S_) do {                                                        \
    bf16x8 af_[4], bf_[4];                                                   \
    _Pragma("unroll") for (int m = 0; m < 4; ++m)                            \
      af_[m] = *(const bf16x8*)(stg + (S_) * 8192 + aIdx + m * 512);         \
    _Pragma("unroll") for (int n = 0; n < 4; ++n)                            \
      bf_[n] = *(const bf16x8*)(stg + (S_) * 8192 + bIdx + n * 512);         \
    __builtin_amdgcn_s_setprio(1);                                           \
    _Pragma("unroll") for (int m = 0; m < 4; ++m)                            \
      _Pragma("unroll") for (int n = 0; n < 4; ++n)                          \
        acc[m][n] = __builtin_amdgcn_mfma_f32_16x16x32_bf16(                 \
            af_[m], bf_[n], acc[m][n], 0, 0, 0);                             \
    __builtin_amdgcn_s_setprio(0);                                           \
  } while (0)

#define BAR __builtin_amdgcn_s_barrier()
#define SB  __builtin_amdgcn_sched_barrier(0)
#define VMC(N_) asm volatile("s_waitcnt vmcnt(" #N_ ")" ::: "memory")

  // K-loop: 8 tiles of BK=32; tile t reads slot t%3, stages t+2 -> (t+2)%3
  STAGE(0, 0); STAGE(32, 1);
  VMC(4); BAR;
  SB; STAGE(64, 2);  RDMM(0); VMC(4); BAR;
  SB; STAGE(96, 0);  RDMM(1); VMC(4); BAR;
  SB; STAGE(128, 1); RDMM(2); VMC(4); BAR;
  SB; STAGE(160, 2); RDMM(0); VMC(4); BAR;
  SB; STAGE(192, 0); RDMM(1); VMC(4); BAR;
  SB; STAGE(224, 1); RDMM(2); VMC(4); BAR;
  SB; RDMM(0); VMC(0); BAR;
  SB; RDMM(1);
  BAR;                                       // staging dead; safe to alias

#undef VMC
#undef SB
#undef RDMM
#undef STAGE

  // ---- write U tile to LDS as f32 [row][col], stride 132 ----
  {
    const int cb = l & 15, rb2 = (l >> 4) * 4;
#pragma unroll
    for (int m = 0; m < 4; ++m)
#pragma unroll
      for (int n = 0; n < 4; ++n) {
        const int row = wm * 64 + m * 16 + rb2;
        const int col = wn * 64 + n * 16 + cb;
#pragma unroll
        for (int jj = 0; jj < 4; ++jj)
          Ub[(row + jj) * 132 + col] = acc[m][n][jj];
      }
  }
  __syncthreads();

  // ---- combine: emit k = 62*mt + kl (kl 1..62; tile 0 also kl=0) ----
  const size_t ob = (size_t)b * 1026 * 4097;
  for (int kl = (mt == 0 ? w : 1 + w); kl <= 62; kl += 4) {
    const int k = 62 * mt + kl;
    if (k > 512) break;
#pragma unroll
    for (int fb = 0; fb < 128; fb += 64) {
      const int floc = fb + l;
      const int f = gb + floc;
      const bool valid = (floc <= 124) && (f <= NFR - 1);
      float zr[3], zi[3];
#pragma unroll
      for (int d = 0; d < 3; ++d) {
        int kk = k - 1 + d;                 // global kappa
        int klr = kl - 1 + d;               // local row-pair index
        bool cj = false;
        if (kk < 0) { kk = 1; klr = kl + 1; cj = true; }   // Z[-1]=conj Z[1]
        const float* up = Ub + (klr * 2) * 132 + floc;     // re row
        const float u0r = up[0], u1r = up[1], u2r = up[2], u3r = up[3];
        const float* vp = up + 132;                        // im row
        const float u0i = vp[0], u1i = vp[1], u2i = vp[2], u3i = vp[3];
        float Zr, Zi;
        switch (kk & 3) {                   // (-i)^(kk*q) sign classes
          case 0:  Zr = u0r + u1r + u2r + u3r;       Zi = u0i + u1i + u2i + u3i;       break;
          case 1:  Zr = (u0r - u2r) + (u1i - u3i);   Zi = (u0i - u2i) - (u1r - u3r);   break;
          case 2:  Zr = u0r - u1r + u2r - u3r;       Zi = u0i - u1i + u2i - u3i;       break;
          default: Zr = (u0r - u2r) - (u1i - u3i);   Zi = (u0i - u2i) + (u1r - u3r);   break;
        }
        zr[d] = Zr;
        zi[d] = cj ? -Zi : Zi;
      }
      const float Yr = 0.5f * zr[1] - 0.25f * (zr[0] + zr[2]);
      const float Yi = 0.5f * zi[1] - 0.25f * (zi[0] + zi[2]);
      if (valid) {
        out[ob + (size_t)k * NFR + f] = Yr;           // Re row k
        out[ob + (size_t)(513 + k) * NFR + f] = Yi;   // Im row 513+k
      }
    }
  }
#undef BAR
}

extern "C" void kernel_launch(void* const* d_in, const int* in_sizes, int n_in,
                              void* d_out, int out_size, void* d_ws, size_t ws_size,
                              hipStream_t stream) {
  const float* x = (const float*)d_in[0];       // [8, 1048576] f32
  float* out = (float*)d_out;                   // [8, 1026, 4097] f32

  __hip_bfloat16* xpBf = (__hip_bfloat16*)d_ws;                 // NB*XP2 bf16
  __hip_bfloat16* cmat = xpBf + (size_t)NB * XP2;               // MPAD*256 bf16

  dim3 gPad((XP2 / 8 + 255) / 256, NB);
  pad_convert_x8<<<gPad, 256, 0, stream>>>(x, xpBf);

  build_cmat<<<(MPAD * 256) / 256, 256, 0, stream>>>(cmat);

  stft_fgemm<<<NWG2, 256, 0, stream>>>(cmat, xpBf, out);
}

// Round 11
// 86.314 us; speedup vs baseline: 12.2761x; 1.1736x over previous
//
#include <hip/hip_runtime.h>
#include <hip/hip_bf16.h>

// ---------------- problem constants ----------------
#define T_LEN 1048576
#define FL    1024
#define PADL  512
#define HOP   256
#define NFR   4097            // frames per batch
#define NB    8
#define XP2   1049600         // reflect-padded length per batch = 4100*256
#define NSEG  4100            // segments per batch
#define MROWS 1028            // 2*(513+1) interleaved re/im rows, k=0..513
#define MPAD  1152            // padded C-matrix rows
#define MTL   9               // M-tiles (stride 124 rows = 62 k)
#define FTL   33              // frame-tiles per batch (stride 125 frames)
#define NTL   264             // FTL*NB
#define NWG2  2376            // MTL*NTL (divisible by 8)

typedef __bf16 bf16x8 __attribute__((ext_vector_type(8)));
typedef float  f32x4  __attribute__((ext_vector_type(4)));

__device__ __forceinline__ void gload16(const __hip_bfloat16* g, void* l) {
  __builtin_amdgcn_global_load_lds(
      (const __attribute__((address_space(1))) unsigned int*)g,
      (__attribute__((address_space(3))) unsigned int*)l, 16, 0, 0);
}

// ---------------- prep: reflect-pad x, convert to bf16 (8 elems/thread) ----------------
__global__ __launch_bounds__(256) void pad_convert_x8(
    const float* __restrict__ x, __hip_bfloat16* __restrict__ xp) {
  const int base = (blockIdx.x * 256 + threadIdx.x) * 8;
  const int b = blockIdx.y;
  if (base >= XP2) return;
  const float* __restrict__ xb = x + (size_t)b * T_LEN;
  union { bf16x8 v; __hip_bfloat16 h[8]; } o;
  if (base >= PADL && base + 8 <= PADL + T_LEN) {
    const float4 v0 = *(const float4*)&xb[base - PADL];
    const float4 v1 = *(const float4*)&xb[base - PADL + 4];
    o.h[0] = __float2bfloat16(v0.x); o.h[1] = __float2bfloat16(v0.y);
    o.h[2] = __float2bfloat16(v0.z); o.h[3] = __float2bfloat16(v0.w);
    o.h[4] = __float2bfloat16(v1.x); o.h[5] = __float2bfloat16(v1.y);
    o.h[6] = __float2bfloat16(v1.z); o.h[7] = __float2bfloat16(v1.w);
    *(bf16x8*)&xp[(size_t)b * XP2 + base] = o.v;
  } else {
    for (int e = 0; e < 8; ++e) {
      const int i = base + e;
      if (i < XP2) {
        const int t = i - PADL;
        const int idx = (t < 0) ? -t : ((t >= T_LEN) ? (2 * T_LEN - 2 - t) : t);
        xp[(size_t)b * XP2 + i] = __float2bfloat16(xb[idx]);
      }
    }
  }
}

// ---------------- prep: build segment-DFT matrix, bf16 [MPAD][256] ----------------
__global__ __launch_bounds__(256) void build_cmat(__hip_bfloat16* __restrict__ cm) {
  const int idx = blockIdx.x * 256 + threadIdx.x;   // over MPAD*256
  if (idx >= MPAD * 256) return;
  const int row = idx >> 8, r = idx & 255;
  float v = 0.f;
  if (row < MROWS) {
    const int k = row >> 1;
    const int ph = (k * r) & 1023;
    const float ang = (float)ph * 6.2831853071795864769f / 1024.f;
    v = (row & 1) ? -sinf(ang) : cosf(ang);
  }
  cm[idx] = __float2bfloat16(v);
}

// ---------------- fused segment-GEMM + vectorized hann-conv combine ----------------
__global__ __launch_bounds__(256, 2) void stft_fgemm(
    const __hip_bfloat16* __restrict__ Cm,  // [MPAD][256]
    const __hip_bfloat16* __restrict__ X,   // [NB][XP2]
    float* __restrict__ out) {              // [NB][1026][4097]
  __shared__ char ldsraw[128 * 132 * 4];    // 67584 B; staging aliases first 48 KB
  __hip_bfloat16* stg = (__hip_bfloat16*)ldsraw;
  float* Ub = (float*)ldsraw;

  // XCD swizzle (2376 % 8 == 0); consecutive wg share the N-tile (B reuse)
  const int orig = blockIdx.x;
  const int wg = (orig & 7) * (NWG2 / 8) + (orig >> 3);
  const int mt = wg % MTL;
  const int nt = wg / MTL;
  const int b = nt / FTL, ft = nt % FTL;
  const int gb = ft * 125;                  // segment/frame base
  const int RB = mt * 124;                  // C-matrix row base
  const int kbase = 62 * mt;                // kappa of local row-pair 0

  const int tid = threadIdx.x;
  const int w = tid >> 6, l = tid & 63;     // 4 waves
  const int wm = w >> 1, wn = w & 1;        // 2M x 2N; per-wave 64x64

  // ---- staging addressing (pre-swizzled global source, linear LDS dest) ----
  const int g_log = (l & 3) ^ ((l >> 3) & 3);
  const int srow = l >> 2;
  const __hip_bfloat16* aB_[2];
  const __hip_bfloat16* bB_[2];
#pragma unroll
  for (int j = 0; j < 2; ++j) {
    const int c = w * 2 + j;                // chunks 0..7 (16 rows each)
    aB_[j] = Cm + (size_t)(RB + c * 16 + srow) * 256 + g_log * 8;
    int g = gb + c * 16 + srow;
    if (g > NSEG - 1) g = NSEG - 1;         // clamp (outputs guarded)
    bB_[j] = X + (size_t)b * XP2 + (size_t)g * 256 + g_log * 8;
  }

  // ---- fragment read addressing (swizzled; verified conflict-free) ----
  const int swz = ((l >> 4) ^ ((l >> 1) & 3)) * 8;
  const int aIdx = (wm * 64 + (l & 15)) * 32 + swz;          // + m*512
  const int bIdx = 4096 + (wn * 64 + (l & 15)) * 32 + swz;   // + n*512

  f32x4 acc[4][4] = {};

#define STAGE(K0_, S_) do {                                                  \
    _Pragma("unroll") for (int j = 0; j < 2; ++j) {                          \
      const int c_ = w * 2 + j;                                              \
      gload16(aB_[j] + (K0_), (void*)(stg + (S_) * 8192 + c_ * 512));        \
      gload16(bB_[j] + (K0_), (void*)(stg + (S_) * 8192 + 4096 + c_ * 512)); \
    }                                                                        \
  } while (0)

#define RDMM(S_) do {                                                        \
    bf16x8 af_[4], bf_[4];                                                   \
    _Pragma("unroll") for (int m = 0; m < 4; ++m)                            \
      af_[m] = *(const bf16x8*)(stg + (S_) * 8192 + aIdx + m * 512);         \
    _Pragma("unroll") for (int n = 0; n < 4; ++n)                            \
      bf_[n] = *(const bf16x8*)(stg + (S_) * 8192 + bIdx + n * 512);         \
    __builtin_amdgcn_s_setprio(1);                                           \
    _Pragma("unroll") for (int m = 0; m < 4; ++m)                            \
      _Pragma("unroll") for (int n = 0; n < 4; ++n)                          \
        acc[m][n] = __builtin_amdgcn_mfma_f32_16x16x32_bf16(                 \
            af_[m], bf_[n], acc[m][n], 0, 0, 0);                             \
    __builtin_amdgcn_s_setprio(0);                                           \
  } while (0)

#define BAR __builtin_amdgcn_s_barrier()
#define SB  __builtin_amdgcn_sched_barrier(0)
#define VMC(N_) asm volatile("s_waitcnt vmcnt(" #N_ ")" ::: "memory")

  // K-loop: 8 tiles of BK=32; tile t reads slot t%3, stages t+2 -> (t+2)%3
  STAGE(0, 0); STAGE(32, 1);
  VMC(4); BAR;
  SB; STAGE(64, 2);  RDMM(0); VMC(4); BAR;
  SB; STAGE(96, 0);  RDMM(1); VMC(4); BAR;
  SB; STAGE(128, 1); RDMM(2); VMC(4); BAR;
  SB; STAGE(160, 2); RDMM(0); VMC(4); BAR;
  SB; STAGE(192, 0); RDMM(1); VMC(4); BAR;
  SB; STAGE(224, 1); RDMM(2); VMC(4); BAR;
  SB; RDMM(0); VMC(0); BAR;
  SB; RDMM(1);

#undef VMC
#undef SB
#undef RDMM
#undef STAGE

  __syncthreads();                          // staging dead; alias as f32 U

  // ---- write U tile to LDS as f32 [row][col], stride 132 ----
  {
    const int cb = l & 15, rb2 = (l >> 4) * 4;
#pragma unroll
    for (int m = 0; m < 4; ++m)
#pragma unroll
      for (int n = 0; n < 4; ++n) {
        const int row = wm * 64 + m * 16 + rb2;
        const int col = wn * 64 + n * 16 + cb;
#pragma unroll
        for (int jj = 0; jj < 4; ++jj)
          Ub[(row + jj) * 132 + col] = acc[m][n][jj];
      }
  }
  __syncthreads();

  // ---- pass A: Z[k,f] = sum_q (-i)^(kq) U[k,f+q], vectorized, in place ----
  // cell = it*256+tid -> row-pair rp = cell>>5 (0..63), col group g4 = (cell&31)*4
  f32x4 zre[8], zim[8];
#pragma unroll
  for (int it = 0; it < 8; ++it) {
    const int cell = it * 256 + tid;
    const int rp = cell >> 5;
    const int g4 = (cell & 31) * 4;
    const float* rr = Ub + (rp * 2) * 132 + g4;
    const f32x4 r0 = *(const f32x4*)rr;
    const f32x4 r1 = *(const f32x4*)(rr + 4);
    const f32x4 i0 = *(const f32x4*)(rr + 132);
    const f32x4 i1 = *(const f32x4*)(rr + 136);
    const float ur[8] = {r0[0], r0[1], r0[2], r0[3], r1[0], r1[1], r1[2], r1[3]};
    const float ui[8] = {i0[0], i0[1], i0[2], i0[3], i1[0], i1[1], i1[2], i1[3]};
    const int cls = (kbase + rp) & 3;
    const float s = (cls & 2) ? -1.f : 1.f;
    const bool odd = cls & 1;
    f32x4 zr, zi;
#pragma unroll
    for (int j = 0; j < 4; ++j) {
      const float p  = ur[j] - ur[j + 2], q  = ur[j] + ur[j + 2];
      const float pi = ui[j] - ui[j + 2], qi = ui[j] + ui[j + 2];
      const float rm = ur[j + 1] - ur[j + 3], rp_ = ur[j + 1] + ur[j + 3];
      const float sm = ui[j + 1] - ui[j + 3], sp = ui[j + 1] + ui[j + 3];
      zr[j] = odd ? (p + s * sm) : (q + s * rp_);
      zi[j] = odd ? (pi - s * rm) : (qi + s * sp);
    }
    zre[it] = zr; zim[it] = zi;
  }
  __syncthreads();
#pragma unroll
  for (int it = 0; it < 8; ++it) {
    const int cell = it * 256 + tid;
    const int rp = cell >> 5;
    const int g4 = (cell & 31) * 4;
    *(f32x4*)(Ub + (rp * 2) * 132 + g4) = zre[it];
    *(f32x4*)(Ub + (rp * 2 + 1) * 132 + g4) = zim[it];
  }
  __syncthreads();

  // ---- pass B: Y[k] = 0.5 Z[k] - 0.25 (Z[k-1] + Z[k+1]); guarded stores ----
  const size_t ob = (size_t)b * 1026 * 4097;
#pragma unroll
  for (int it = 0; it < 8; ++it) {
    const int cell = it * 256 + tid;
    if (cell < 62 * 32) {
      const int kl = 1 + (cell >> 5);
      const int g4 = (cell & 31) * 4;
      const int k = kbase + kl;
      if (k <= 512) {
        const float* zp = Ub + (kl * 2) * 132 + g4;
        const f32x4 z0r = *(const f32x4*)zp;
        const f32x4 z0i = *(const f32x4*)(zp + 132);
        const f32x4 zmr = *(const f32x4*)(zp - 264);
        const f32x4 zmi = *(const f32x4*)(zp - 132);
        const f32x4 zpr = *(const f32x4*)(zp + 264);
        const f32x4 zpi = *(const f32x4*)(zp + 396);
        const f32x4 Yr = 0.5f * z0r - 0.25f * (zmr + zpr);
        const f32x4 Yi = 0.5f * z0i - 0.25f * (zmi + zpi);
        const int f0 = gb + g4;
        float* orow = out + ob + (size_t)k * NFR;
        float* irow = out + ob + (size_t)(513 + k) * NFR;
#pragma unroll
        for (int j = 0; j < 4; ++j) {
          if (g4 + j <= 124 && f0 + j <= NFR - 1) {
            orow[f0 + j] = Yr[j];
            irow[f0 + j] = Yi[j];
          }
        }
      }
    }
  }
  // k = 0 edge (mt==0): Yr = 0.5 Zr0 - 0.5 Zr1, Yi = 0.5 Zi0
  if (mt == 0 && tid < 32) {
    const int g4 = tid * 4;
    const f32x4 z0r = *(const f32x4*)(Ub + g4);
    const f32x4 z0i = *(const f32x4*)(Ub + 132 + g4);
    const f32x4 z1r = *(const f32x4*)(Ub + 264 + g4);
    const int f0 = gb + g4;
#pragma unroll
    for (int j = 0; j < 4; ++j) {
      if (g4 + j <= 124 && f0 + j <= NFR - 1) {
        out[ob + f0 + j] = 0.5f * z0r[j] - 0.5f * z1r[j];
        out[ob + (size_t)513 * NFR + f0 + j] = 0.5f * z0i[j];
      }
    }
  }
#undef BAR
}

extern "C" void kernel_launch(void* const* d_in, const int* in_sizes, int n_in,
                              void* d_out, int out_size, void* d_ws, size_t ws_size,
                              hipStream_t stream) {
  const float* x = (const float*)d_in[0];       // [8, 1048576] f32
  float* out = (float*)d_out;                   // [8, 1026, 4097] f32

  __hip_bfloat16* xpBf = (__hip_bfloat16*)d_ws;                 // NB*XP2 bf16
  __hip_bfloat16* cmat = xpBf + (size_t)NB * XP2;               // MPAD*256 bf16

  dim3 gPad((XP2 / 8 + 255) / 256, NB);
  pad_convert_x8<<<gPad, 256, 0, stream>>>(x, xpBf);

  build_cmat<<<(MPAD * 256) / 256, 256, 0, stream>>>(cmat);

  stft_fgemm<<<NWG2, 256, 0, stream>>>(cmat, xpBf, out);
}

// Round 12
// 84.551 us; speedup vs baseline: 12.5321x; 1.0209x over previous
//
#include <hip/hip_runtime.h>
#include <hip/hip_bf16.h>

// ---------------- problem constants ----------------
#define T_LEN 1048576
#define FL    1024
#define PADL  512
#define HOP   256
#define NFR   4097            // frames per batch
#define NB    8
#define XP2   1049600         // reflect-padded length per batch = 4100*256
#define NSEG  4100            // segments per batch
#define MROWS 1028            // 2*(513+1) interleaved re/im rows, k=0..513
#define MPAD  1152            // padded C-matrix rows
#define MTL   9               // M-tiles (stride 124 rows = 62 k)
#define FTL   33              // frame-tiles per batch (stride 125 frames)
#define NTL   264             // FTL*NB
#define NWG2  2376            // MTL*NTL (divisible by 8)

typedef __bf16 bf16x8 __attribute__((ext_vector_type(8)));
typedef float  f32x4  __attribute__((ext_vector_type(4)));

__device__ __forceinline__ void gload16(const __hip_bfloat16* g, void* l) {
  __builtin_amdgcn_global_load_lds(
      (const __attribute__((address_space(1))) unsigned int*)g,
      (__attribute__((address_space(3))) unsigned int*)l, 16, 0, 0);
}

// ---------------- prep: reflect-pad x, convert to bf16 (8 elems/thread) ----------------
__global__ __launch_bounds__(256) void pad_convert_x8(
    const float* __restrict__ x, __hip_bfloat16* __restrict__ xp) {
  const int base = (blockIdx.x * 256 + threadIdx.x) * 8;
  const int b = blockIdx.y;
  if (base >= XP2) return;
  const float* __restrict__ xb = x + (size_t)b * T_LEN;
  union { bf16x8 v; __hip_bfloat16 h[8]; } o;
  if (base >= PADL && base + 8 <= PADL + T_LEN) {
    const float4 v0 = *(const float4*)&xb[base - PADL];
    const float4 v1 = *(const float4*)&xb[base - PADL + 4];
    o.h[0] = __float2bfloat16(v0.x); o.h[1] = __float2bfloat16(v0.y);
    o.h[2] = __float2bfloat16(v0.z); o.h[3] = __float2bfloat16(v0.w);
    o.h[4] = __float2bfloat16(v1.x); o.h[5] = __float2bfloat16(v1.y);
    o.h[6] = __float2bfloat16(v1.z); o.h[7] = __float2bfloat16(v1.w);
    *(bf16x8*)&xp[(size_t)b * XP2 + base] = o.v;
  } else {
    for (int e = 0; e < 8; ++e) {
      const int i = base + e;
      if (i < XP2) {
        const int t = i - PADL;
        const int idx = (t < 0) ? -t : ((t >= T_LEN) ? (2 * T_LEN - 2 - t) : t);
        xp[(size_t)b * XP2 + i] = __float2bfloat16(xb[idx]);
      }
    }
  }
}

// ---------------- prep: build segment-DFT matrix, bf16 [MPAD][256] ----------------
__global__ __launch_bounds__(256) void build_cmat(__hip_bfloat16* __restrict__ cm) {
  const int idx = blockIdx.x * 256 + threadIdx.x;   // over MPAD*256
  if (idx >= MPAD * 256) return;
  const int row = idx >> 8, r = idx & 255;
  float v = 0.f;
  if (row < MROWS) {
    const int k = row >> 1;
    const int ph = (k * r) & 1023;
    const float ang = (float)ph * 6.2831853071795864769f / 1024.f;
    v = (row & 1) ? -sinf(ang) : cosf(ang);
  }
  cm[idx] = __float2bfloat16(v);
}

// ---------------- fused segment-GEMM + combine; producer/consumer waves ----------------
// Waves 0-3: GEMM compute (2Mx2N, per-wave 64x64, acc[4][4]); waves 4-7:
// staging producers (own the vmcnt ledger). Combine: all 8 waves, 4 cells
// each; pass B takes Z[k] from registers, reads only Z[k+-1] from LDS.
__global__ __launch_bounds__(512, 2) void stft_fgemm(
    const __hip_bfloat16* __restrict__ Cm,  // [MPAD][256]
    const __hip_bfloat16* __restrict__ X,   // [NB][XP2]
    float* __restrict__ out) {              // [NB][1026][4097]
  __shared__ char ldsraw[128 * 132 * 4];    // 67584 B; staging aliases first 48 KB
  __hip_bfloat16* stg = (__hip_bfloat16*)ldsraw;
  float* Ub = (float*)ldsraw;

  // XCD swizzle; consecutive wg share the N-tile (B-panel L2 reuse)
  const int orig = blockIdx.x;
  const int wg = (orig & 7) * (NWG2 / 8) + (orig >> 3);
  const int mt = wg % MTL;
  const int nt = wg / MTL;
  const int b = nt / FTL, ft = nt % FTL;
  const int gb = ft * 125;                  // segment/frame base
  const int RB = mt * 124;                  // C-matrix row base
  const int kbase = 62 * mt;                // kappa of local row-pair 0

  const int tid = threadIdx.x;
  const int w = tid >> 6, l = tid & 63;     // 8 waves
  const bool isProd = w >= 4;
  const int cw = w & 3;                     // role-local wave id
  const int wm = cw >> 1, wn = cw & 1;      // compute: 2M x 2N, 64x64/wave

  // ---- staging addressing (producers; pre-swizzled source, linear dest) ----
  const int g_log = (l & 3) ^ ((l >> 3) & 3);
  const int srow = l >> 2;
  const __hip_bfloat16* aB_[2];
  const __hip_bfloat16* bB_[2];
#pragma unroll
  for (int j = 0; j < 2; ++j) {
    const int c = cw * 2 + j;               // chunks 0..7 (16 rows each)
    aB_[j] = Cm + (size_t)(RB + c * 16 + srow) * 256 + g_log * 8;
    int g = gb + c * 16 + srow;
    if (g > NSEG - 1) g = NSEG - 1;         // clamp (outputs guarded)
    bB_[j] = X + (size_t)b * XP2 + (size_t)g * 256 + g_log * 8;
  }

  // ---- fragment read addressing (swizzled; conflict-free) ----
  const int swz = ((l >> 4) ^ ((l >> 1) & 3)) * 8;
  const int aIdx = (wm * 64 + (l & 15)) * 32 + swz;          // + m*512
  const int bIdx = 4096 + (wn * 64 + (l & 15)) * 32 + swz;   // + n*512

  f32x4 acc[4][4] = {};

#define STAGE(K0_, S_) do {                                                  \
    _Pragma("unroll") for (int j = 0; j < 2; ++j) {                          \
      const int c_ = cw * 2 + j;                                             \
      gload16(aB_[j] + (K0_), (void*)(stg + (S_) * 8192 + c_ * 512));        \
      gload16(bB_[j] + (K0_), (void*)(stg + (S_) * 8192 + 4096 + c_ * 512)); \
    }                                                                        \
  } while (0)

#define RDMM(S_) do {                                                        \
    bf16x8 af_[4], bf_[4];                                                   \
    _Pragma("unroll") for (int m = 0; m < 4; ++m)                            \
      af_[m] = *(const bf16x8*)(stg + (S_) * 8192 + aIdx + m * 512);         \
    _Pragma("unroll") for (int n = 0; n < 4; ++n)                            \
      bf_[n] = *(const bf16x8*)(stg + (S_) * 8192 + bIdx + n * 512);         \
    __builtin_amdgcn_s_setprio(1);                                           \
    _Pragma("unroll") for (int m = 0; m < 4; ++m)                            \
      _Pragma("unroll") for (int n = 0; n < 4; ++n)                          \
        acc[m][n] = __builtin_amdgcn_mfma_f32_16x16x32_bf16(                 \
            af_[m], bf_[n], acc[m][n], 0, 0, 0);                             \
    __builtin_amdgcn_s_setprio(0);                                           \
  } while (0)

#define BAR __builtin_amdgcn_s_barrier()
#define SB  __builtin_amdgcn_sched_barrier(0)
#define VMC(N_) asm volatile("s_waitcnt vmcnt(" #N_ ")" ::: "memory")

  // 8 k-tiles of BK=32; tile t reads slot t%3; producers stage t+2 -> (t+2)%3.
  // Barrier counts: producer 9, compute 9 (matched).
  if (isProd) {
    STAGE(0, 0); STAGE(32, 1); VMC(4); BAR;      // tile 0 landed
    SB; STAGE(64, 2);  VMC(4); BAR;              // t=0: tile 1 landed
    SB; STAGE(96, 0);  VMC(4); BAR;              // t=1
    SB; STAGE(128, 1); VMC(4); BAR;              // t=2
    SB; STAGE(160, 2); VMC(4); BAR;              // t=3
    SB; STAGE(192, 0); VMC(4); BAR;              // t=4
    SB; STAGE(224, 1); VMC(4); BAR;              // t=5: tile 6 landed
    VMC(0); BAR;                                 // t=6: tile 7 landed
    BAR;                                         // t=7
  } else {
    BAR;
    SB; RDMM(0); BAR;    // t=0
    SB; RDMM(1); BAR;    // t=1
    SB; RDMM(2); BAR;    // t=2
    SB; RDMM(0); BAR;    // t=3
    SB; RDMM(1); BAR;    // t=4
    SB; RDMM(2); BAR;    // t=5
    SB; RDMM(0); BAR;    // t=6
    SB; RDMM(1); BAR;    // t=7
  }
  __syncthreads();                          // staging dead; alias as f32 U

#undef VMC
#undef SB
#undef RDMM
#undef STAGE

  // ---- write U tile to LDS as f32 [row][col], stride 132 (waves 0-3) ----
  if (!isProd) {
    const int cb = l & 15, rb2 = (l >> 4) * 4;
#pragma unroll
    for (int m = 0; m < 4; ++m)
#pragma unroll
      for (int n = 0; n < 4; ++n) {
        const int row = wm * 64 + m * 16 + rb2;
        const int col = wn * 64 + n * 16 + cb;
#pragma unroll
        for (int jj = 0; jj < 4; ++jj)
          Ub[(row + jj) * 132 + col] = acc[m][n][jj];
      }
  }
  __syncthreads();

  // ---- pass A: Z[k,f] = sum_q (-i)^(kq) U[k,f+q]; all 8 waves, 4 cells ----
  f32x4 zre[4], zim[4];
#pragma unroll
  for (int it = 0; it < 4; ++it) {
    const int cell = it * 512 + tid;
    const int rp = cell >> 5;               // 0..63
    const int g4 = (cell & 31) * 4;
    const float* rr = Ub + (rp * 2) * 132 + g4;
    const f32x4 r0 = *(const f32x4*)rr;
    const f32x4 r1 = *(const f32x4*)(rr + 4);
    const f32x4 i0 = *(const f32x4*)(rr + 132);
    const f32x4 i1 = *(const f32x4*)(rr + 136);
    const float ur[8] = {r0[0], r0[1], r0[2], r0[3], r1[0], r1[1], r1[2], r1[3]};
    const float ui[8] = {i0[0], i0[1], i0[2], i0[3], i1[0], i1[1], i1[2], i1[3]};
    const int cls = (kbase + rp) & 3;
    const float s = (cls & 2) ? -1.f : 1.f;
    const bool odd = cls & 1;
    f32x4 zr, zi;
#pragma unroll
    for (int j = 0; j < 4; ++j) {
      const float p  = ur[j] - ur[j + 2], q  = ur[j] + ur[j + 2];
      const float pi = ui[j] - ui[j + 2], qi = ui[j] + ui[j + 2];
      const float rm = ur[j + 1] - ur[j + 3], rp_ = ur[j + 1] + ur[j + 3];
      const float sm = ui[j + 1] - ui[j + 3], sp = ui[j + 1] + ui[j + 3];
      zr[j] = odd ? (p + s * sm) : (q + s * rp_);
      zi[j] = odd ? (pi - s * rm) : (qi + s * sp);
    }
    zre[it] = zr; zim[it] = zi;
  }
  __syncthreads();
#pragma unroll
  for (int it = 0; it < 4; ++it) {
    const int cell = it * 512 + tid;
    const int rp = cell >> 5;
    const int g4 = (cell & 31) * 4;
    *(f32x4*)(Ub + (rp * 2) * 132 + g4) = zre[it];
    *(f32x4*)(Ub + (rp * 2 + 1) * 132 + g4) = zim[it];
  }
  __syncthreads();

  // ---- pass B: Y[k] = 0.5 Z[k] - 0.25 (Z[k-1]+Z[k+1]); Z[k] from regs ----
  const size_t ob = (size_t)b * 1026 * 4097;
#pragma unroll
  for (int it = 0; it < 4; ++it) {
    const int cell = it * 512 + tid;
    const int rp = cell >> 5;
    const int g4 = (cell & 31) * 4;
    const int k = kbase + rp;
    const int f0 = gb + g4;
    if (rp >= 1 && rp <= 62 && k <= 512) {
      const float* zp = Ub + rp * 264 + g4;           // this row-pair base
      const f32x4 zmr = *(const f32x4*)(zp - 264);
      const f32x4 zmi = *(const f32x4*)(zp - 132);
      const f32x4 zpr = *(const f32x4*)(zp + 264);
      const f32x4 zpi = *(const f32x4*)(zp + 396);
      const f32x4 Yr = 0.5f * zre[it] - 0.25f * (zmr + zpr);
      const f32x4 Yi = 0.5f * zim[it] - 0.25f * (zmi + zpi);
      float* orow = out + ob + (size_t)k * NFR;
      float* irow = out + ob + (size_t)(513 + k) * NFR;
#pragma unroll
      for (int j = 0; j < 4; ++j) {
        if (g4 + j <= 124 && f0 + j <= NFR - 1) {
          orow[f0 + j] = Yr[j];
          irow[f0 + j] = Yi[j];
        }
      }
    } else if (mt == 0 && rp == 0) {
      // k = 0 edge: Yr = 0.5 Zr0 - 0.5 Zr1, Yi = 0.5 Zi0
      const f32x4 z1r = *(const f32x4*)(Ub + 264 + g4);
#pragma unroll
      for (int j = 0; j < 4; ++j) {
        if (g4 + j <= 124 && f0 + j <= NFR - 1) {
          out[ob + f0 + j] = 0.5f * zre[it][j] - 0.5f * z1r[j];
          out[ob + (size_t)513 * NFR + f0 + j] = 0.5f * zim[it][j];
        }
      }
    }
  }
#undef BAR
}

extern "C" void kernel_launch(void* const* d_in, const int* in_sizes, int n_in,
                              void* d_out, int out_size, void* d_ws, size_t ws_size,
                              hipStream_t stream) {
  const float* x = (const float*)d_in[0];       // [8, 1048576] f32
  float* out = (float*)d_out;                   // [8, 1026, 4097] f32

  __hip_bfloat16* xpBf = (__hip_bfloat16*)d_ws;                 // NB*XP2 bf16
  __hip_bfloat16* cmat = xpBf + (size_t)NB * XP2;               // MPAD*256 bf16

  dim3 gPad((XP2 / 8 + 255) / 256, NB);
  pad_convert_x8<<<gPad, 256, 0, stream>>>(x, xpBf);

  build_cmat<<<(MPAD * 256) / 256, 256, 0, stream>>>(cmat);

  stft_fgemm<<<NWG2, 512, 0, stream>>>(cmat, xpBf, out);
}

// Round 13
// 59.339 us; speedup vs baseline: 17.8566x; 1.4249x over previous
//
#include <hip/hip_runtime.h>
#include <hip/hip_bf16.h>

// ---------------- problem constants ----------------
#define T_LEN 1048576
#define FL    1024
#define PADL  512
#define HOP   256
#define NFR   4097            // frames per batch
#define NB    8
#define XP2   1049600         // reflect-padded length per batch = 4100*256
#define NSEG  4100            // segments per batch
#define MROWS 1028            // 2*(513+1) interleaved re/im rows, k=0..513
#define MPAD  1152            // padded C-matrix rows
#define MTL   9               // M-tiles (stride 62 k)
#define FTL   34              // frame-tiles per batch (stride 124 frames -> aligned stores)
#define NTL   272             // FTL*NB
#define NWG2  2448            // MTL*NTL (divisible by 8)

typedef __bf16 bf16x8 __attribute__((ext_vector_type(8)));
typedef float  f32x4  __attribute__((ext_vector_type(4)));

__device__ __forceinline__ void gload16(const __hip_bfloat16* g, void* l) {
  __builtin_amdgcn_global_load_lds(
      (const __attribute__((address_space(1))) unsigned int*)g,
      (__attribute__((address_space(3))) unsigned int*)l, 16, 0, 0);
}

// ---------------- prep: reflect-pad x, convert to bf16 (8 elems/thread) ----------------
__global__ __launch_bounds__(256) void pad_convert_x8(
    const float* __restrict__ x, __hip_bfloat16* __restrict__ xp) {
  const int base = (blockIdx.x * 256 + threadIdx.x) * 8;
  const int b = blockIdx.y;
  if (base >= XP2) return;
  const float* __restrict__ xb = x + (size_t)b * T_LEN;
  union { bf16x8 v; __hip_bfloat16 h[8]; } o;
  if (base >= PADL && base + 8 <= PADL + T_LEN) {
    const float4 v0 = *(const float4*)&xb[base - PADL];
    const float4 v1 = *(const float4*)&xb[base - PADL + 4];
    o.h[0] = __float2bfloat16(v0.x); o.h[1] = __float2bfloat16(v0.y);
    o.h[2] = __float2bfloat16(v0.z); o.h[3] = __float2bfloat16(v0.w);
    o.h[4] = __float2bfloat16(v1.x); o.h[5] = __float2bfloat16(v1.y);
    o.h[6] = __float2bfloat16(v1.z); o.h[7] = __float2bfloat16(v1.w);
    *(bf16x8*)&xp[(size_t)b * XP2 + base] = o.v;
  } else {
    for (int e = 0; e < 8; ++e) {
      const int i = base + e;
      if (i < XP2) {
        const int t = i - PADL;
        const int idx = (t < 0) ? -t : ((t >= T_LEN) ? (2 * T_LEN - 2 - t) : t);
        xp[(size_t)b * XP2 + i] = __float2bfloat16(xb[idx]);
      }
    }
  }
}

// ---------------- prep: build segment-DFT matrix, bf16 [MPAD][256] ----------------
__global__ __launch_bounds__(256) void build_cmat(__hip_bfloat16* __restrict__ cm) {
  const int idx = blockIdx.x * 256 + threadIdx.x;   // over MPAD*256
  if (idx >= MPAD * 256) return;
  const int row = idx >> 8, r = idx & 255;
  float v = 0.f;
  if (row < MROWS) {
    const int k = row >> 1;
    const int ph = (k * r) & 1023;
    const float ang = (float)ph * 6.2831853071795864769f / 1024.f;
    v = (row & 1) ? -sinf(ang) : cosf(ang);
  }
  cm[idx] = __float2bfloat16(v);
}

// ---------------- fused segment-GEMM + combine; producer/consumer waves ----------------
// Waves 0-3: GEMM compute (2Mx2N, 64x64/wave); waves 4-7: staging producers
// (own the vmcnt ledger; compute never waits vmem). 4 sub-slots of 16 KB;
// BK=64 super-tiles -> only 4 barriers in the GEMM. Combine: all 8 waves,
// pass B Z[k] from regs; 124-stride tiles give 16B-aligned f32x4 stores.
__global__ __launch_bounds__(512, 2) void stft_fgemm(
    const __hip_bfloat16* __restrict__ Cm,  // [MPAD][256]
    const __hip_bfloat16* __restrict__ X,   // [NB][XP2]
    float* __restrict__ out) {              // [NB][1026][4097]
  __shared__ char ldsraw[128 * 132 * 4];    // 67584 B; staging aliases first 64 KB
  __hip_bfloat16* stg = (__hip_bfloat16*)ldsraw;
  float* Ub = (float*)ldsraw;

  // XCD swizzle (2448 % 8 == 0); consecutive wg share the N-tile (B reuse)
  const int orig = blockIdx.x;
  const int wg = (orig & 7) * (NWG2 / 8) + (orig >> 3);
  const int mt = wg % MTL;
  const int nt = wg / MTL;
  const int b = nt / FTL, ft = nt % FTL;
  const int gb = ft * 124;                  // segment/frame base (mod 4 == 0)
  const int RB = mt * 124;                  // C-matrix row base
  const int kbase = 62 * mt;                // kappa of local row-pair 0

  const int tid = threadIdx.x;
  const int w = tid >> 6, l = tid & 63;     // 8 waves
  const bool isProd = w >= 4;
  const int cw = w & 3;                     // role-local wave id
  const int wm = cw >> 1, wn = cw & 1;      // compute: 2M x 2N, 64x64/wave

  // ---- staging addressing (producers; pre-swizzled source, linear dest) ----
  const int g_log = (l & 3) ^ ((l >> 3) & 3);
  const int srow = l >> 2;
  const __hip_bfloat16* aB_[2];
  const __hip_bfloat16* bB_[2];
#pragma unroll
  for (int j = 0; j < 2; ++j) {
    const int c = cw * 2 + j;               // chunks 0..7 (16 rows each)
    aB_[j] = Cm + (size_t)(RB + c * 16 + srow) * 256 + g_log * 8;
    int g = gb + c * 16 + srow;
    if (g > NSEG - 1) g = NSEG - 1;         // clamp (outputs guarded)
    bB_[j] = X + (size_t)b * XP2 + (size_t)g * 256 + g_log * 8;
  }

  // ---- fragment read addressing (swizzled; conflict-free) ----
  const int swz = ((l >> 4) ^ ((l >> 1) & 3)) * 8;
  const int aIdx = (wm * 64 + (l & 15)) * 32 + swz;          // + m*512
  const int bIdx = 4096 + (wn * 64 + (l & 15)) * 32 + swz;   // + n*512

  f32x4 acc[4][4] = {};

#define STAGE(K0_, S_) do {                                                  \
    _Pragma("unroll") for (int j = 0; j < 2; ++j) {                          \
      const int c_ = cw * 2 + j;                                             \
      gload16(aB_[j] + (K0_), (void*)(stg + (S_) * 8192 + c_ * 512));        \
      gload16(bB_[j] + (K0_), (void*)(stg + (S_) * 8192 + 4096 + c_ * 512)); \
    }                                                                        \
  } while (0)

#define RDMM(S_) do {                                                        \
    bf16x8 af_[4], bf_[4];                                                   \
    _Pragma("unroll") for (int m = 0; m < 4; ++m)                            \
      af_[m] = *(const bf16x8*)(stg + (S_) * 8192 + aIdx + m * 512);         \
    _Pragma("unroll") for (int n = 0; n < 4; ++n)                            \
      bf_[n] = *(const bf16x8*)(stg + (S_) * 8192 + bIdx + n * 512);         \
    __builtin_amdgcn_s_setprio(1);                                           \
    _Pragma("unroll") for (int m = 0; m < 4; ++m)                            \
      _Pragma("unroll") for (int n = 0; n < 4; ++n)                          \
        acc[m][n] = __builtin_amdgcn_mfma_f32_16x16x32_bf16(                 \
            af_[m], bf_[n], acc[m][n], 0, 0, 0);                             \
    __builtin_amdgcn_s_setprio(0);                                           \
  } while (0)

#define BAR __builtin_amdgcn_s_barrier()
#define SB  __builtin_amdgcn_sched_barrier(0)
#define VMC(N_) asm volatile("s_waitcnt vmcnt(" #N_ ")" ::: "memory")

  // 4 BK=64 super-tiles over sub-slots {0,1,2,3}; producers own vmcnt.
  // Windows: [BAR0: rd 0,1][BAR1: rd 2,3 | st 0,1][BAR2: rd 0,1 | st 2,3][BAR3: rd 2,3]
  if (isProd) {
    STAGE(0, 0); STAGE(32, 1); STAGE(64, 2); STAGE(96, 3);
    VMC(8);  BAR;                           // sub 0,1 landed
    VMC(0);  BAR;                           // sub 2,3 landed
    SB; STAGE(128, 0); STAGE(160, 1);
    VMC(0);  BAR;                           // new 0,1 landed
    SB; STAGE(192, 2); STAGE(224, 3);
    VMC(0);  BAR;                           // new 2,3 landed
  } else {
    BAR;
    SB; RDMM(0); RDMM(1); BAR;
    SB; RDMM(2); RDMM(3); BAR;
    SB; RDMM(0); RDMM(1); BAR;
    SB; RDMM(2); RDMM(3);
  }
  __syncthreads();                          // staging dead; alias as f32 U

#undef VMC
#undef SB
#undef RDMM
#undef STAGE

  // ---- write U tile to LDS as f32 [row][col], stride 132 (waves 0-3) ----
  if (!isProd) {
    const int cb = l & 15, rb2 = (l >> 4) * 4;
#pragma unroll
    for (int m = 0; m < 4; ++m)
#pragma unroll
      for (int n = 0; n < 4; ++n) {
        const int row = wm * 64 + m * 16 + rb2;
        const int col = wn * 64 + n * 16 + cb;
#pragma unroll
        for (int jj = 0; jj < 4; ++jj)
          Ub[(row + jj) * 132 + col] = acc[m][n][jj];
      }
  }
  __syncthreads();

  // ---- pass A: Z[k,f] = sum_q (-i)^(kq) U[k,f+q]; all 8 waves, 4 cells ----
  f32x4 zre[4], zim[4];
#pragma unroll
  for (int it = 0; it < 4; ++it) {
    const int cell = it * 512 + tid;
    const int rp = cell >> 5;               // 0..63
    const int g4 = (cell & 31) * 4;
    const float* rr = Ub + (rp * 2) * 132 + g4;
    const f32x4 r0 = *(const f32x4*)rr;
    const f32x4 r1 = *(const f32x4*)(rr + 4);
    const f32x4 i0 = *(const f32x4*)(rr + 132);
    const f32x4 i1 = *(const f32x4*)(rr + 136);
    const float ur[8] = {r0[0], r0[1], r0[2], r0[3], r1[0], r1[1], r1[2], r1[3]};
    const float ui[8] = {i0[0], i0[1], i0[2], i0[3], i1[0], i1[1], i1[2], i1[3]};
    const int cls = (kbase + rp) & 3;
    const float s = (cls & 2) ? -1.f : 1.f;
    const bool odd = cls & 1;
    f32x4 zr, zi;
#pragma unroll
    for (int j = 0; j < 4; ++j) {
      const float p  = ur[j] - ur[j + 2], q  = ur[j] + ur[j + 2];
      const float pi = ui[j] - ui[j + 2], qi = ui[j] + ui[j + 2];
      const float rm = ur[j + 1] - ur[j + 3], rp_ = ur[j + 1] + ur[j + 3];
      const float sm = ui[j + 1] - ui[j + 3], sp = ui[j + 1] + ui[j + 3];
      zr[j] = odd ? (p + s * sm) : (q + s * rp_);
      zi[j] = odd ? (pi - s * rm) : (qi + s * sp);
    }
    zre[it] = zr; zim[it] = zi;
  }
  __syncthreads();
#pragma unroll
  for (int it = 0; it < 4; ++it) {
    const int cell = it * 512 + tid;
    const int rp = cell >> 5;
    const int g4 = (cell & 31) * 4;
    *(f32x4*)(Ub + (rp * 2) * 132 + g4) = zre[it];
    *(f32x4*)(Ub + (rp * 2 + 1) * 132 + g4) = zim[it];
  }
  __syncthreads();

  // ---- pass B: Y[k] = 0.5 Z[k] - 0.25 (Z[k-1]+Z[k+1]); Z[k] from regs ----
  // output cols 0..123 of this tile (g4 <= 120); f0 16B-aligned
  const size_t ob = (size_t)b * 1026 * 4097;
#pragma unroll
  for (int it = 0; it < 4; ++it) {
    const int cell = it * 512 + tid;
    const int rp = cell >> 5;
    const int g4 = (cell & 31) * 4;
    const int k = kbase + rp;
    const int f0 = gb + g4;
    if (g4 <= 120) {
      if (rp >= 1 && rp <= 62 && k <= 512) {
        const float* zp = Ub + rp * 264 + g4;         // this row-pair base
        const f32x4 zmr = *(const f32x4*)(zp - 264);
        const f32x4 zmi = *(const f32x4*)(zp - 132);
        const f32x4 zpr = *(const f32x4*)(zp + 264);
        const f32x4 zpi = *(const f32x4*)(zp + 396);
        const f32x4 Yr = 0.5f * zre[it] - 0.25f * (zmr + zpr);
        const f32x4 Yi = 0.5f * zim[it] - 0.25f * (zmi + zpi);
        float* orow = out + ob + (size_t)k * NFR;
        float* irow = out + ob + (size_t)(513 + k) * NFR;
        if (f0 + 3 <= NFR - 1) {
          *(f32x4*)&orow[f0] = Yr;
          *(f32x4*)&irow[f0] = Yi;
        } else {
#pragma unroll
          for (int j = 0; j < 4; ++j)
            if (f0 + j <= NFR - 1) { orow[f0 + j] = Yr[j]; irow[f0 + j] = Yi[j]; }
        }
      } else if (mt == 0 && rp == 0) {
        // k = 0 edge: Yr = 0.5 Zr0 - 0.5 Zr1, Yi = 0.5 Zi0
        const f32x4 z1r = *(const f32x4*)(Ub + 264 + g4);
        const f32x4 Yr = 0.5f * zre[it] - 0.5f * z1r;
        const f32x4 Yi = 0.5f * zim[it];
        if (f0 + 3 <= NFR - 1) {
          *(f32x4*)&out[ob + f0] = Yr;
          *(f32x4*)&out[ob + (size_t)513 * NFR + f0] = Yi;
        } else {
#pragma unroll
          for (int j = 0; j < 4; ++j)
            if (f0 + j <= NFR - 1) {
              out[ob + f0 + j] = Yr[j];
              out[ob + (size_t)513 * NFR + f0 + j] = Yi[j];
            }
        }
      }
    }
  }
#undef BAR
}

extern "C" void kernel_launch(void* const* d_in, const int* in_sizes, int n_in,
                              void* d_out, int out_size, void* d_ws, size_t ws_size,
                              hipStream_t stream) {
  const float* x = (const float*)d_in[0];       // [8, 1048576] f32
  float* out = (float*)d_out;                   // [8, 1026, 4097] f32

  __hip_bfloat16* xpBf = (__hip_bfloat16*)d_ws;                 // NB*XP2 bf16
  __hip_bfloat16* cmat = xpBf + (size_t)NB * XP2;               // MPAD*256 bf16

  dim3 gPad((XP2 / 8 + 255) / 256, NB);
  pad_convert_x8<<<gPad, 256, 0, stream>>>(x, xpBf);

  build_cmat<<<(MPAD * 256) / 256, 256, 0, stream>>>(cmat);

  stft_fgemm<<<NWG2, 512, 0, stream>>>(cmat, xpBf, out);
}